// Round 9
// baseline (327.788 us; speedup 1.0000x reference)
//
#include <hip/hip_runtime.h>
#include <hip/hip_bf16.h>

#define D_HID 128
#define D_OUT 100
#define BN_EPS 1e-5f
#define XP 136              // padded LDS row (bf16 elems) -> 272 B
#define ROWB 272

typedef short bf16x8 __attribute__((ext_vector_type(8)));
typedef float f32x4 __attribute__((ext_vector_type(4)));

// ---------------- helpers ----------------
__device__ __forceinline__ unsigned fmap(float f) {
    unsigned u = __float_as_uint(f);
    return (u & 0x80000000u) ? ~u : (u | 0x80000000u);
}
__device__ __forceinline__ float funmap(unsigned u) {
    return __uint_as_float((u & 0x80000000u) ? (u ^ 0x80000000u) : ~u);
}
#define NEG_INF_MAPPED 0x007FFFFFu

__device__ __forceinline__ unsigned short f2bf(float f) {  // RNE f32->bf16
    unsigned u = __float_as_uint(f);
    return (unsigned short)((u + 0x7fffu + ((u >> 16) & 1u)) >> 16);
}
__device__ __forceinline__ unsigned packbf2(float x, float y) {
    return (unsigned)f2bf(x) | ((unsigned)f2bf(y) << 16);
}
__device__ __forceinline__ float2 unpackbf2(unsigned v) {
    float2 r;
    r.x = __uint_as_float(v << 16);
    r.y = __uint_as_float(v & 0xffff0000u);
    return r;
}

// first n in [0,N] with off[n]+n >= target  (off[n]+n strictly increasing)
__device__ __forceinline__ int balanced_lb(const int* __restrict__ off, int N, long long target) {
    int lo = 0, hi = N;
    while (lo < hi) {
        int mid = (lo + hi) >> 1;
        if ((long long)off[mid] + mid < target) lo = mid + 1; else hi = mid;
    }
    return lo;
}

// ---------------- init ----------------
__global__ __launch_bounds__(256) void init_k(int* deg, int* cursor, unsigned* pool,
                                              float* bnsum, float* bnsq, int N, int P) {
    int i = blockIdx.x * 256 + threadIdx.x;
    if (i < N) { deg[i] = 0; cursor[i] = 0; }
    if (i < P) pool[i] = NEG_INF_MAPPED;
    if (i < 128) { bnsum[i] = 0.f; bnsq[i] = 0.f; }
}

__global__ __launch_bounds__(256) void deg_k(const int* __restrict__ dst, int* deg, int E) {
    int e = blockIdx.x * 256 + threadIdx.x;
    if (e < E) atomicAdd(&deg[dst[e]], 1);
}

// ---------------- exclusive scan over deg -> off (2-level) ----------------
#define SCAN_EPB 1024
__global__ __launch_bounds__(256) void scan1_k(const int* __restrict__ deg, int* __restrict__ off,
                                               int* __restrict__ btot, int N) {
    __shared__ int ts[256];
    int base = blockIdx.x * SCAN_EPB + threadIdx.x * 4;
    int v[4];
    int s = 0;
#pragma unroll
    for (int j = 0; j < 4; ++j) { int idx = base + j; v[j] = (idx < N) ? deg[idx] : 0; s += v[j]; }
    ts[threadIdx.x] = s;
    __syncthreads();
    for (int d = 1; d < 256; d <<= 1) {
        int t = (threadIdx.x >= d) ? ts[threadIdx.x - d] : 0;
        __syncthreads();
        ts[threadIdx.x] += t;
        __syncthreads();
    }
    int excl = ts[threadIdx.x] - s;
#pragma unroll
    for (int j = 0; j < 4; ++j) { int idx = base + j; if (idx < N) off[idx] = excl; excl += v[j]; }
    if (threadIdx.x == 255) btot[blockIdx.x] = ts[255];
}

__global__ __launch_bounds__(256) void scan2_k(int* btot, int nb, int* off, int N, int E) {
    __shared__ int ts[256];
    int v = (threadIdx.x < nb) ? btot[threadIdx.x] : 0;
    ts[threadIdx.x] = v;
    __syncthreads();
    for (int d = 1; d < 256; d <<= 1) {
        int t = (threadIdx.x >= d) ? ts[threadIdx.x - d] : 0;
        __syncthreads();
        ts[threadIdx.x] += t;
        __syncthreads();
    }
    if (threadIdx.x < nb) btot[threadIdx.x] = ts[threadIdx.x] - v;  // exclusive
    if (threadIdx.x == 0) off[N] = E;
}

__global__ __launch_bounds__(256) void scan3_dinv_k(int* off, const int* __restrict__ btot,
                                                    const int* __restrict__ deg,
                                                    float* __restrict__ dinv, int N) {
    int i = blockIdx.x * 256 + threadIdx.x;
    if (i < N) {
        off[i] += btot[i / SCAN_EPB];
        dinv[i] = rsqrtf((float)(1 + deg[i]));
    }
}

__global__ __launch_bounds__(256) void fill_k(const int* __restrict__ src, const int* __restrict__ dst,
                                              const int* __restrict__ off, int* cursor,
                                              int* __restrict__ csr, int E) {
    int e = blockIdx.x * 256 + threadIdx.x;
    if (e < E) {
        int d = dst[e];
        int p = atomicAdd(&cursor[d], 1);
        csr[off[d] + p] = src[e];
    }
}

// ---------------- prep: transpose weights to bf16 [col][k] ----------------
__global__ __launch_bounds__(256) void prepW_k(const float* __restrict__ W1,
                                               const float* __restrict__ W2,
                                               unsigned short* __restrict__ W1t,
                                               unsigned short* __restrict__ W2t) {
    int t = blockIdx.x * 256 + threadIdx.x;
    if (t < 16384) { int n = t >> 7, k = t & 127; W1t[t] = f2bf(W1[k * 128 + n]); }
    if (t < 14336) { int c = t >> 7, k = t & 127; W2t[t] = (c < D_OUT) ? f2bf(W2[k * D_OUT + c]) : (unsigned short)0; }
}

// ---------------- GEMM1 (MFMA): H' = dinv .* bf16(X @ W1) ----------------
__global__ __launch_bounds__(256) void gemm1_k(const float* __restrict__ X,
                                               const unsigned short* __restrict__ W1t,
                                               const float* __restrict__ dinv,
                                               unsigned* __restrict__ H, int N) {
    __shared__ char smem[64 * ROWB + 128 * ROWB];
    char* Xs = smem;
    char* Wt = smem + 64 * ROWB;
    int tid = threadIdx.x;
    int row0 = blockIdx.x * 64;
    {
        const uint4* Wg = (const uint4*)W1t;
#pragma unroll
        for (int i = 0; i < 8; ++i) {
            int idx = i * 256 + tid;
            uint4 u = Wg[idx];
            *(uint4*)(Wt + (idx >> 4) * ROWB + (idx & 15) * 16) = u;
        }
    }
    {
        const float4* Xg = (const float4*)X;
#pragma unroll
        for (int i = 0; i < 8; ++i) {
            int idx = i * 256 + tid;
            int r = idx >> 5, c4 = idx & 31;
            int grow = row0 + r; if (grow >= N) grow = N - 1;
            float4 v = Xg[(long long)grow * 32 + c4];
            uint2 o; o.x = packbf2(v.x, v.y); o.y = packbf2(v.z, v.w);
            *(uint2*)(Xs + r * ROWB + c4 * 8) = o;
        }
    }
    __syncthreads();
    int w = tid >> 6, l = tid & 63;
    int arow = w * 16 + (l & 15);
    int koff = (l >> 4) * 16;
    f32x4 acc[8];
#pragma unroll
    for (int ct = 0; ct < 8; ++ct)
#pragma unroll
        for (int r = 0; r < 4; ++r) acc[ct][r] = 0.f;
#pragma unroll
    for (int ks = 0; ks < 4; ++ks) {
        int kb = ks * 64 + koff;
        bf16x8 a = *(const bf16x8*)(Xs + arow * ROWB + kb);
#pragma unroll
        for (int ct = 0; ct < 8; ++ct) {
            bf16x8 b = *(const bf16x8*)(Wt + (ct * 16 + (l & 15)) * ROWB + kb);
            acc[ct] = __builtin_amdgcn_mfma_f32_16x16x32_bf16(a, b, acc[ct], 0, 0, 0);
        }
    }
    __syncthreads();
    {
        int crow0 = w * 16 + (l >> 4) * 4;
        int ccol = l & 15;
#pragma unroll
        for (int ct = 0; ct < 8; ++ct)
#pragma unroll
            for (int r = 0; r < 4; ++r)
                *(unsigned short*)(Xs + (crow0 + r) * ROWB + (ct * 16 + ccol) * 2) = f2bf(acc[ct][r]);
    }
    __syncthreads();
#pragma unroll
    for (int i = 0; i < 16; ++i) {
        int idx = i * 256 + tid;
        int r = idx >> 6, cu = idx & 63;
        int grow = row0 + r;
        if (grow < N) {
            float2 f = unpackbf2(*(unsigned*)(Xs + r * ROWB + cu * 4));
            float d = dinv[grow];
            H[(long long)grow * 64 + cu] = packbf2(f.x * d, f.y * d);
        }
    }
}

// ---------------- agg1: X1 = dinv .* (H' + sum_nbr H'), fused BN stats ----------------
// One 64-lane wave per group; edge-balanced node ranges via binary search on off[].
#define A1_FLUSH_ADV()                                                  \
    do {                                                                \
        float ox = dncur * acc.x, oy = dncur * acc.y;                   \
        X1[(long long)n * 64 + lane] = packbf2(ox, oy);                 \
        bs.x += ox; bs.y += oy;                                         \
        bq.x += ox * ox; bq.y += oy * oy;                               \
        ++n;                                                            \
        nend = off[n + 1];                                              \
        dncur = dinv[n];                                                \
        acc = unpackbf2(hnext);                                         \
        int np_ = (n + 1 < N) ? (n + 1) : (N - 1);                      \
        hnext = H[(long long)np_ * 64 + lane];                          \
    } while (0)

__global__ __launch_bounds__(256) void agg1_k(const unsigned* __restrict__ H,
                                              const int* __restrict__ off,
                                              const int* __restrict__ csr,
                                              const float* __restrict__ dinv,
                                              unsigned* __restrict__ X1,
                                              float* bnsum, float* bnsq,
                                              int N, int E, int ngrp) {
    int grp = blockIdx.x * 4 + (threadIdx.x >> 6);
    int lane = threadIdx.x & 63;
    long long total = (long long)E + N;
    int n0 = balanced_lb(off, N, total * grp / ngrp);
    int n1 = balanced_lb(off, N, total * (grp + 1) / ngrp);
    float2 bs; bs.x = 0.f; bs.y = 0.f;
    float2 bq; bq.x = 0.f; bq.y = 0.f;
    if (n0 < n1) {
        int n = n0;
        int i = off[n0];
        int eend = off[n1];
        int nend = off[n0 + 1];
        float dncur = dinv[n0];
        float2 acc = unpackbf2(H[(long long)n0 * 64 + lane]);
        int np0 = (n0 + 1 < N) ? (n0 + 1) : (N - 1);
        unsigned hnext = H[(long long)np0 * 64 + lane];
        while (i + 8 <= eend) {
            int s0 = csr[i], s1 = csr[i + 1], s2 = csr[i + 2], s3 = csr[i + 3];
            int s4 = csr[i + 4], s5 = csr[i + 5], s6 = csr[i + 6], s7 = csr[i + 7];
            unsigned g0 = H[(long long)s0 * 64 + lane];
            unsigned g1 = H[(long long)s1 * 64 + lane];
            unsigned g2 = H[(long long)s2 * 64 + lane];
            unsigned g3 = H[(long long)s3 * 64 + lane];
            unsigned g4 = H[(long long)s4 * 64 + lane];
            unsigned g5 = H[(long long)s5 * 64 + lane];
            unsigned g6 = H[(long long)s6 * 64 + lane];
            unsigned g7 = H[(long long)s7 * 64 + lane];
            while (i >= nend) A1_FLUSH_ADV();
            { float2 f = unpackbf2(g0); acc.x += f.x; acc.y += f.y; }
            while (i + 1 >= nend) A1_FLUSH_ADV();
            { float2 f = unpackbf2(g1); acc.x += f.x; acc.y += f.y; }
            while (i + 2 >= nend) A1_FLUSH_ADV();
            { float2 f = unpackbf2(g2); acc.x += f.x; acc.y += f.y; }
            while (i + 3 >= nend) A1_FLUSH_ADV();
            { float2 f = unpackbf2(g3); acc.x += f.x; acc.y += f.y; }
            while (i + 4 >= nend) A1_FLUSH_ADV();
            { float2 f = unpackbf2(g4); acc.x += f.x; acc.y += f.y; }
            while (i + 5 >= nend) A1_FLUSH_ADV();
            { float2 f = unpackbf2(g5); acc.x += f.x; acc.y += f.y; }
            while (i + 6 >= nend) A1_FLUSH_ADV();
            { float2 f = unpackbf2(g6); acc.x += f.x; acc.y += f.y; }
            while (i + 7 >= nend) A1_FLUSH_ADV();
            { float2 f = unpackbf2(g7); acc.x += f.x; acc.y += f.y; }
            i += 8;
        }
        while (i < eend) {
            int s0 = csr[i];
            unsigned g0 = H[(long long)s0 * 64 + lane];
            while (i >= nend) A1_FLUSH_ADV();
            { float2 f = unpackbf2(g0); acc.x += f.x; acc.y += f.y; }
            ++i;
        }
        for (;;) {  // trailing flushes
            float ox = dncur * acc.x, oy = dncur * acc.y;
            X1[(long long)n * 64 + lane] = packbf2(ox, oy);
            bs.x += ox; bs.y += oy;
            bq.x += ox * ox; bq.y += oy * oy;
            ++n;
            if (n >= n1) break;
            dncur = dinv[n];
            acc = unpackbf2(hnext);
            int np_ = (n + 1 < N) ? (n + 1) : (N - 1);
            hnext = H[(long long)np_ * 64 + lane];
        }
    }
    __shared__ float2 ls[256], lq[256];
    ls[threadIdx.x] = bs; lq[threadIdx.x] = bq;
    __syncthreads();
    if (threadIdx.x < 64) {
        float2 s = ls[threadIdx.x], q = lq[threadIdx.x];
#pragma unroll
        for (int j = 64; j < 256; j += 64) {
            float2 a = ls[threadIdx.x + j], b = lq[threadIdx.x + j];
            s.x += a.x; s.y += a.y; q.x += b.x; q.y += b.y;
        }
        atomicAdd(&bnsum[threadIdx.x * 2 + 0], s.x);
        atomicAdd(&bnsum[threadIdx.x * 2 + 1], s.y);
        atomicAdd(&bnsq[threadIdx.x * 2 + 0], q.x);
        atomicAdd(&bnsq[threadIdx.x * 2 + 1], q.y);
    }
}

__global__ __launch_bounds__(128) void bnfinal_k(const float* bnsum, const float* bnsq,
                                                 const float* __restrict__ gamma,
                                                 const float* __restrict__ beta,
                                                 float* scale, float* shift, int N) {
    int c = threadIdx.x;
    float mu = bnsum[c] / (float)N;
    float var = bnsq[c] / (float)N - mu * mu;
    var = var > 0.f ? var : 0.f;
    float sc = gamma[c] * rsqrtf(var + BN_EPS);
    scale[c] = sc;
    shift[c] = beta[c] - mu * sc;
}

// ---------------- GEMM2 (MFMA): H2' = dinv .* bf16(relu(BN(X1)) @ W2) ----------------
__global__ __launch_bounds__(256) void gemm2_k(const unsigned* __restrict__ X1,
                                               const unsigned short* __restrict__ W2t,
                                               const float* __restrict__ scale,
                                               const float* __restrict__ shift,
                                               const float* __restrict__ dinv,
                                               unsigned* __restrict__ H2, int N) {
    __shared__ char smem[64 * ROWB + 112 * ROWB];
    __shared__ float scs[128], shs[128];
    char* Xs = smem;
    char* Wt = smem + 64 * ROWB;
    int tid = threadIdx.x;
    int row0 = blockIdx.x * 64;
    if (tid < 128) { scs[tid] = scale[tid]; shs[tid] = shift[tid]; }
    {
        const uint4* Wg = (const uint4*)W2t;
#pragma unroll
        for (int i = 0; i < 7; ++i) {
            int idx = i * 256 + tid;
            uint4 u = Wg[idx];
            *(uint4*)(Wt + (idx >> 4) * ROWB + (idx & 15) * 16) = u;
        }
    }
    __syncthreads();
    {
        const uint4* Xg = (const uint4*)X1;
#pragma unroll
        for (int i = 0; i < 4; ++i) {
            int idx = i * 256 + tid;
            int r = idx >> 4, kc = idx & 15;
            int grow = row0 + r; if (grow >= N) grow = N - 1;
            uint4 u = Xg[(long long)grow * 16 + kc];
            uint4 o;
#pragma unroll
            for (int jj = 0; jj < 4; ++jj) {
                float2 f = unpackbf2((&u.x)[jj]);
                int k = kc * 8 + jj * 2;
                float v0 = f.x * scs[k] + shs[k];
                float v1 = f.y * scs[k + 1] + shs[k + 1];
                (&o.x)[jj] = packbf2(v0 > 0.f ? v0 : 0.f, v1 > 0.f ? v1 : 0.f);
            }
            *(uint4*)(Xs + r * ROWB + kc * 16) = o;
        }
    }
    __syncthreads();
    int w = tid >> 6, l = tid & 63;
    int arow = w * 16 + (l & 15);
    int koff = (l >> 4) * 16;
    f32x4 acc[7];
#pragma unroll
    for (int ct = 0; ct < 7; ++ct)
#pragma unroll
        for (int r = 0; r < 4; ++r) acc[ct][r] = 0.f;
#pragma unroll
    for (int ks = 0; ks < 4; ++ks) {
        int kb = ks * 64 + koff;
        bf16x8 a = *(const bf16x8*)(Xs + arow * ROWB + kb);
#pragma unroll
        for (int ct = 0; ct < 7; ++ct) {
            bf16x8 b = *(const bf16x8*)(Wt + (ct * 16 + (l & 15)) * ROWB + kb);
            acc[ct] = __builtin_amdgcn_mfma_f32_16x16x32_bf16(a, b, acc[ct], 0, 0, 0);
        }
    }
    __syncthreads();
    {
        int crow0 = w * 16 + (l >> 4) * 4;
        int ccol = l & 15;
#pragma unroll
        for (int ct = 0; ct < 7; ++ct)
#pragma unroll
            for (int r = 0; r < 4; ++r)
                *(unsigned short*)(Xs + (crow0 + r) * ROWB + (ct * 16 + ccol) * 2) = f2bf(acc[ct][r]);
    }
    __syncthreads();
#pragma unroll
    for (int i = 0; i < 13; ++i) {
        int idx = i * 256 + tid;
        if (idx < 3200) {
            int r = idx / 50, cu = idx - r * 50;
            int grow = row0 + r;
            if (grow < N) {
                float2 f = unpackbf2(*(unsigned*)(Xs + r * ROWB + cu * 4));
                float d = dinv[grow];
                H2[(long long)grow * 50 + cu] = packbf2(f.x * d, f.y * d);
            }
        }
    }
}

// ---------------- agg2 + bias + segment_max pool (batch sorted, edge-balanced) ----------------
#define NINF (-__builtin_inff())
#define A2_FLUSH_ADV()                                                  \
    do {                                                                \
        float vx_ = dncur * acc.x + bf.x, vy_ = dncur * acc.y + bf.y;   \
        int gb_ = batch[n];                                             \
        if (gb_ != gcur) {                                              \
            long long pb_ = (long long)gcur * D_OUT + lane * 2;         \
            atomicMax(&pool[pb_], fmap(mx));                            \
            atomicMax(&pool[pb_ + 1], fmap(my));                        \
            gcur = gb_; mx = NINF; my = NINF;                           \
        }                                                               \
        mx = mx > vx_ ? mx : vx_; my = my > vy_ ? my : vy_;             \
        ++n;                                                            \
        nend = off[n + 1];                                              \
        dncur = dinv[n];                                                \
        acc = unpackbf2(hnext);                                         \
        int np_ = (n + 1 < N) ? (n + 1) : (N - 1);                      \
        hnext = H2[(long long)np_ * 50 + lane];                         \
    } while (0)

__global__ __launch_bounds__(256) void agg2pool_k(const unsigned* __restrict__ H2,
                                                  const int* __restrict__ off,
                                                  const int* __restrict__ csr,
                                                  const float* __restrict__ dinv,
                                                  const int* __restrict__ batch,
                                                  const float* __restrict__ b2,
                                                  unsigned* __restrict__ pool,
                                                  int N, int E, int ngrp) {
    int grp = blockIdx.x * 4 + (threadIdx.x >> 6);
    int lane = threadIdx.x & 63;
    if (lane >= 50) return;
    long long total = (long long)E + N;
    int n0 = balanced_lb(off, N, total * grp / ngrp);
    int n1 = balanced_lb(off, N, total * (grp + 1) / ngrp);
    if (n0 >= n1) return;
    float2 bf = ((const float2*)b2)[lane];
    float mx = NINF, my = NINF;
    int gcur = batch[n0];
    int n = n0;
    int i = off[n0];
    int eend = off[n1];
    int nend = off[n0 + 1];
    float dncur = dinv[n0];
    float2 acc = unpackbf2(H2[(long long)n0 * 50 + lane]);
    int np0 = (n0 + 1 < N) ? (n0 + 1) : (N - 1);
    unsigned hnext = H2[(long long)np0 * 50 + lane];
    while (i + 8 <= eend) {
        int s0 = csr[i], s1 = csr[i + 1], s2 = csr[i + 2], s3 = csr[i + 3];
        int s4 = csr[i + 4], s5 = csr[i + 5], s6 = csr[i + 6], s7 = csr[i + 7];
        unsigned g0 = H2[(long long)s0 * 50 + lane];
        unsigned g1 = H2[(long long)s1 * 50 + lane];
        unsigned g2 = H2[(long long)s2 * 50 + lane];
        unsigned g3 = H2[(long long)s3 * 50 + lane];
        unsigned g4 = H2[(long long)s4 * 50 + lane];
        unsigned g5 = H2[(long long)s5 * 50 + lane];
        unsigned g6 = H2[(long long)s6 * 50 + lane];
        unsigned g7 = H2[(long long)s7 * 50 + lane];
        while (i >= nend) A2_FLUSH_ADV();
        { float2 f = unpackbf2(g0); acc.x += f.x; acc.y += f.y; }
        while (i + 1 >= nend) A2_FLUSH_ADV();
        { float2 f = unpackbf2(g1); acc.x += f.x; acc.y += f.y; }
        while (i + 2 >= nend) A2_FLUSH_ADV();
        { float2 f = unpackbf2(g2); acc.x += f.x; acc.y += f.y; }
        while (i + 3 >= nend) A2_FLUSH_ADV();
        { float2 f = unpackbf2(g3); acc.x += f.x; acc.y += f.y; }
        while (i + 4 >= nend) A2_FLUSH_ADV();
        { float2 f = unpackbf2(g4); acc.x += f.x; acc.y += f.y; }
        while (i + 5 >= nend) A2_FLUSH_ADV();
        { float2 f = unpackbf2(g5); acc.x += f.x; acc.y += f.y; }
        while (i + 6 >= nend) A2_FLUSH_ADV();
        { float2 f = unpackbf2(g6); acc.x += f.x; acc.y += f.y; }
        while (i + 7 >= nend) A2_FLUSH_ADV();
        { float2 f = unpackbf2(g7); acc.x += f.x; acc.y += f.y; }
        i += 8;
    }
    while (i < eend) {
        int s0 = csr[i];
        unsigned g0 = H2[(long long)s0 * 50 + lane];
        while (i >= nend) A2_FLUSH_ADV();
        { float2 f = unpackbf2(g0); acc.x += f.x; acc.y += f.y; }
        ++i;
    }
    for (;;) {  // trailing flushes
        float vx_ = dncur * acc.x + bf.x, vy_ = dncur * acc.y + bf.y;
        int gb_ = batch[n];
        if (gb_ != gcur) {
            long long pb_ = (long long)gcur * D_OUT + lane * 2;
            atomicMax(&pool[pb_], fmap(mx));
            atomicMax(&pool[pb_ + 1], fmap(my));
            gcur = gb_; mx = NINF; my = NINF;
        }
        mx = mx > vx_ ? mx : vx_; my = my > vy_ ? my : vy_;
        ++n;
        if (n >= n1) break;
        dncur = dinv[n];
        acc = unpackbf2(hnext);
        int np_ = (n + 1 < N) ? (n + 1) : (N - 1);
        hnext = H2[(long long)np_ * 50 + lane];
    }
    long long pb = (long long)gcur * D_OUT + lane * 2;
    atomicMax(&pool[pb], fmap(mx));
    atomicMax(&pool[pb + 1], fmap(my));
}

__global__ __launch_bounds__(256) void pool_final_k(const unsigned* __restrict__ pool,
                                                    float* __restrict__ out, int P) {
    int i = blockIdx.x * 256 + threadIdx.x;
    if (i < P) out[i] = funmap(pool[i]);
}

// ---------------- launch ----------------
extern "C" void kernel_launch(void* const* d_in, const int* in_sizes, int n_in,
                              void* d_out, int out_size, void* d_ws, size_t ws_size,
                              hipStream_t stream) {
    const float* X     = (const float*)d_in[0];
    const int*   eidx  = (const int*)d_in[1];
    const int*   batch = (const int*)d_in[2];
    const float* W1    = (const float*)d_in[4];
    // d_in[5] = b1: cancels inside batch_norm
    const float* gamma = (const float*)d_in[6];
    const float* beta  = (const float*)d_in[7];
    const float* W2    = (const float*)d_in[8];
    const float* b2    = (const float*)d_in[9];

    const int N = in_sizes[0] / D_HID;     // 200000
    const int E = in_sizes[1] / 2;         // 600000
    const int P = out_size;                // num_graphs * 100
    const int* src = eidx;
    const int* dst = eidx + E;

    // workspace layout
    char* p = (char*)d_ws;
    auto alloc = [&](size_t bytes) { char* q = p; p += (bytes + 255) & ~(size_t)255; return q; };
    int*      deg    = (int*)alloc((size_t)N * 4);
    int*      cursor = (int*)alloc((size_t)N * 4);
    int*      off    = (int*)alloc((size_t)(N + 1) * 4);
    int*      btot   = (int*)alloc(256 * 4);
    int*      csr    = (int*)alloc((size_t)E * 4);
    float*    dinv   = (float*)alloc((size_t)N * 4);
    float*    bnsum  = (float*)alloc(128 * 4);
    float*    bnsq   = (float*)alloc(128 * 4);
    float*    scale  = (float*)alloc(128 * 4);
    float*    shift  = (float*)alloc(128 * 4);
    unsigned short* W1t = (unsigned short*)alloc(16384 * 2);
    unsigned short* W2t = (unsigned short*)alloc(14336 * 2);
    unsigned* pool   = (unsigned*)alloc((size_t)P * 4);
    unsigned* A      = (unsigned*)alloc((size_t)N * 128 * 2);  // H' bf16 (then H2', stride 100)
    unsigned* B      = (unsigned*)alloc((size_t)N * 128 * 2);  // X1 bf16

    const int nb1 = (N + SCAN_EPB - 1) / SCAN_EPB;
    const int initN = (N > P ? N : P);

    init_k<<<(initN + 255) / 256, 256, 0, stream>>>(deg, cursor, pool, bnsum, bnsq, N, P);
    deg_k<<<(E + 255) / 256, 256, 0, stream>>>(dst, deg, E);
    scan1_k<<<nb1, 256, 0, stream>>>(deg, off, btot, N);
    scan2_k<<<1, 256, 0, stream>>>(btot, nb1, off, N, E);
    scan3_dinv_k<<<(N + 255) / 256, 256, 0, stream>>>(off, btot, deg, dinv, N);
    fill_k<<<(E + 255) / 256, 256, 0, stream>>>(src, dst, off, cursor, csr, E);
    prepW_k<<<64, 256, 0, stream>>>(W1, W2, W1t, W2t);

    const int nblk_g = (N + 63) / 64;
    gemm1_k<<<nblk_g, 256, 0, stream>>>(X, W1t, dinv, A, N);

    const int nblk_agg = 2048;
    const int ngrp = nblk_agg * 4;   // 8192 waves = exact full residency
    agg1_k<<<nblk_agg, 256, 0, stream>>>(A, off, csr, dinv, B, bnsum, bnsq, N, E, ngrp);
    bnfinal_k<<<1, 128, 0, stream>>>(bnsum, bnsq, gamma, beta, scale, shift, N);

    gemm2_k<<<nblk_g, 256, 0, stream>>>(B, W2t, scale, shift, dinv, A, N);

    agg2pool_k<<<nblk_agg, 256, 0, stream>>>(A, off, csr, dinv, batch, b2, pool, N, E, ngrp);
    pool_final_k<<<(P + 255) / 256, 256, 0, stream>>>(pool, (float*)d_out, P);
}

// Round 10
// 310.834 us; speedup vs baseline: 1.0545x; 1.0545x over previous
//
#include <hip/hip_runtime.h>
#include <hip/hip_bf16.h>

#define D_HID 128
#define D_OUT 100
#define BN_EPS 1e-5f
#define XP 136              // padded LDS row (bf16 elems) -> 272 B
#define ROWB 272

typedef short bf16x8 __attribute__((ext_vector_type(8)));
typedef float f32x4 __attribute__((ext_vector_type(4)));

// ---------------- helpers ----------------
__device__ __forceinline__ unsigned fmap(float f) {
    unsigned u = __float_as_uint(f);
    return (u & 0x80000000u) ? ~u : (u | 0x80000000u);
}
__device__ __forceinline__ float funmap(unsigned u) {
    return __uint_as_float((u & 0x80000000u) ? (u ^ 0x80000000u) : ~u);
}
#define NEG_INF_MAPPED 0x007FFFFFu

__device__ __forceinline__ unsigned short f2bf(float f) {  // RNE f32->bf16
    unsigned u = __float_as_uint(f);
    return (unsigned short)((u + 0x7fffu + ((u >> 16) & 1u)) >> 16);
}
__device__ __forceinline__ unsigned packbf2(float x, float y) {
    return (unsigned)f2bf(x) | ((unsigned)f2bf(y) << 16);
}
__device__ __forceinline__ float2 unpackbf2(unsigned v) {
    float2 r;
    r.x = __uint_as_float(v << 16);
    r.y = __uint_as_float(v & 0xffff0000u);
    return r;
}

// ---------------- init (+ weight transpose fused: independent work) ----------------
__global__ __launch_bounds__(256) void init_k(int* deg, int* cursor, unsigned* pool,
                                              float* bnsum, float* bnsq,
                                              const float* __restrict__ W1,
                                              const float* __restrict__ W2,
                                              unsigned short* __restrict__ W1t,
                                              unsigned short* __restrict__ W2t,
                                              int N, int P) {
    int i = blockIdx.x * 256 + threadIdx.x;
    if (i < N) { deg[i] = 0; cursor[i] = 0; }
    if (i < P) pool[i] = NEG_INF_MAPPED;
    if (i < 128) { bnsum[i] = 0.f; bnsq[i] = 0.f; }
    if (i < 16384) { int n = i >> 7, k = i & 127; W1t[i] = f2bf(W1[k * 128 + n]); }
    if (i < 14336) { int c = i >> 7, k = i & 127; W2t[i] = (c < D_OUT) ? f2bf(W2[k * D_OUT + c]) : (unsigned short)0; }
}

__global__ __launch_bounds__(256) void deg_k(const int* __restrict__ dst, int* deg, int E) {
    int e = blockIdx.x * 256 + threadIdx.x;
    if (e < E) atomicAdd(&deg[dst[e]], 1);
}

// ---------------- exclusive scan over deg -> off (2-level) ----------------
#define SCAN_EPB 1024
__global__ __launch_bounds__(256) void scan1_k(const int* __restrict__ deg, int* __restrict__ off,
                                               int* __restrict__ btot, int N) {
    __shared__ int ts[256];
    int base = blockIdx.x * SCAN_EPB + threadIdx.x * 4;
    int v[4];
    int s = 0;
#pragma unroll
    for (int j = 0; j < 4; ++j) { int idx = base + j; v[j] = (idx < N) ? deg[idx] : 0; s += v[j]; }
    ts[threadIdx.x] = s;
    __syncthreads();
    for (int d = 1; d < 256; d <<= 1) {
        int t = (threadIdx.x >= d) ? ts[threadIdx.x - d] : 0;
        __syncthreads();
        ts[threadIdx.x] += t;
        __syncthreads();
    }
    int excl = ts[threadIdx.x] - s;
#pragma unroll
    for (int j = 0; j < 4; ++j) { int idx = base + j; if (idx < N) off[idx] = excl; excl += v[j]; }
    if (threadIdx.x == 255) btot[blockIdx.x] = ts[255];
}

__global__ __launch_bounds__(256) void scan2_k(int* btot, int nb, int* off, int N, int E) {
    __shared__ int ts[256];
    int v = (threadIdx.x < nb) ? btot[threadIdx.x] : 0;
    ts[threadIdx.x] = v;
    __syncthreads();
    for (int d = 1; d < 256; d <<= 1) {
        int t = (threadIdx.x >= d) ? ts[threadIdx.x - d] : 0;
        __syncthreads();
        ts[threadIdx.x] += t;
        __syncthreads();
    }
    if (threadIdx.x < nb) btot[threadIdx.x] = ts[threadIdx.x] - v;  // exclusive
    if (threadIdx.x == 0) off[N] = E;
}

__global__ __launch_bounds__(256) void scan3_dinv_k(int* off, const int* __restrict__ btot,
                                                    const int* __restrict__ deg,
                                                    float* __restrict__ dinv, int N) {
    int i = blockIdx.x * 256 + threadIdx.x;
    if (i < N) {
        off[i] += btot[i / SCAN_EPB];
        dinv[i] = rsqrtf((float)(1 + deg[i]));
    }
}

__global__ __launch_bounds__(256) void fill_k(const int* __restrict__ src, const int* __restrict__ dst,
                                              const int* __restrict__ off, int* cursor,
                                              int* __restrict__ csr, int E) {
    int e = blockIdx.x * 256 + threadIdx.x;
    if (e < E) {
        int d = dst[e];
        int p = atomicAdd(&cursor[d], 1);
        csr[off[d] + p] = src[e];
    }
}

// ---------------- GEMM1 (MFMA): H' = dinv .* bf16(X @ W1) ----------------
__global__ __launch_bounds__(256) void gemm1_k(const float* __restrict__ X,
                                               const unsigned short* __restrict__ W1t,
                                               const float* __restrict__ dinv,
                                               unsigned* __restrict__ H, int N) {
    __shared__ char smem[64 * ROWB + 128 * ROWB];
    char* Xs = smem;
    char* Wt = smem + 64 * ROWB;
    int tid = threadIdx.x;
    int row0 = blockIdx.x * 64;
    {
        const uint4* Wg = (const uint4*)W1t;
#pragma unroll
        for (int i = 0; i < 8; ++i) {
            int idx = i * 256 + tid;
            uint4 u = Wg[idx];
            *(uint4*)(Wt + (idx >> 4) * ROWB + (idx & 15) * 16) = u;
        }
    }
    {
        const float4* Xg = (const float4*)X;
#pragma unroll
        for (int i = 0; i < 8; ++i) {
            int idx = i * 256 + tid;
            int r = idx >> 5, c4 = idx & 31;
            int grow = row0 + r; if (grow >= N) grow = N - 1;
            float4 v = Xg[(long long)grow * 32 + c4];
            uint2 o; o.x = packbf2(v.x, v.y); o.y = packbf2(v.z, v.w);
            *(uint2*)(Xs + r * ROWB + c4 * 8) = o;
        }
    }
    __syncthreads();
    int w = tid >> 6, l = tid & 63;
    int arow = w * 16 + (l & 15);
    int koff = (l >> 4) * 16;
    f32x4 acc[8];
#pragma unroll
    for (int ct = 0; ct < 8; ++ct)
#pragma unroll
        for (int r = 0; r < 4; ++r) acc[ct][r] = 0.f;
#pragma unroll
    for (int ks = 0; ks < 4; ++ks) {
        int kb = ks * 64 + koff;
        bf16x8 a = *(const bf16x8*)(Xs + arow * ROWB + kb);
#pragma unroll
        for (int ct = 0; ct < 8; ++ct) {
            bf16x8 b = *(const bf16x8*)(Wt + (ct * 16 + (l & 15)) * ROWB + kb);
            acc[ct] = __builtin_amdgcn_mfma_f32_16x16x32_bf16(a, b, acc[ct], 0, 0, 0);
        }
    }
    __syncthreads();
    {
        int crow0 = w * 16 + (l >> 4) * 4;
        int ccol = l & 15;
#pragma unroll
        for (int ct = 0; ct < 8; ++ct)
#pragma unroll
            for (int r = 0; r < 4; ++r)
                *(unsigned short*)(Xs + (crow0 + r) * ROWB + (ct * 16 + ccol) * 2) = f2bf(acc[ct][r]);
    }
    __syncthreads();
#pragma unroll
    for (int i = 0; i < 16; ++i) {
        int idx = i * 256 + tid;
        int r = idx >> 6, cu = idx & 63;
        int grow = row0 + r;
        if (grow < N) {
            float2 f = unpackbf2(*(unsigned*)(Xs + r * ROWB + cu * 4));
            float d = dinv[grow];
            H[(long long)grow * 64 + cu] = packbf2(f.x * d, f.y * d);
        }
    }
}

// ---------------- agg1: X1 = dinv .* (H' + sum_nbr H'), fused BN stats ----------------
// One 64-lane wave per group, 1 uint (2 bf16) per lane = 256 B/row; 8 gathers in flight.
#define A1_FLUSH_ADV()                                                  \
    do {                                                                \
        float ox = dncur * acc.x, oy = dncur * acc.y;                   \
        X1[(long long)n * 64 + lane] = packbf2(ox, oy);                 \
        bs.x += ox; bs.y += oy;                                         \
        bq.x += ox * ox; bq.y += oy * oy;                               \
        ++n;                                                            \
        nend = off[n + 1];                                              \
        dncur = dinv[n];                                                \
        acc = unpackbf2(hnext);                                         \
        int np_ = (n + 1 < N) ? (n + 1) : (N - 1);                      \
        hnext = H[(long long)np_ * 64 + lane];                          \
    } while (0)

__global__ __launch_bounds__(256) void agg1_k(const unsigned* __restrict__ H,
                                              const int* __restrict__ off,
                                              const int* __restrict__ csr,
                                              const float* __restrict__ dinv,
                                              unsigned* __restrict__ X1,
                                              float* bnsum, float* bnsq,
                                              int N, int chunk) {
    int grp = blockIdx.x * 4 + (threadIdx.x >> 6);
    int lane = threadIdx.x & 63;
    int n0 = grp * chunk;
    int n1 = n0 + chunk; if (n1 > N) n1 = N;
    float2 bs; bs.x = 0.f; bs.y = 0.f;
    float2 bq; bq.x = 0.f; bq.y = 0.f;
    if (n0 < n1) {
        int n = n0;
        int i = off[n0];
        int eend = off[n1];
        int nend = off[n0 + 1];
        float dncur = dinv[n0];
        float2 acc = unpackbf2(H[(long long)n0 * 64 + lane]);
        int np0 = (n0 + 1 < N) ? (n0 + 1) : (N - 1);
        unsigned hnext = H[(long long)np0 * 64 + lane];
        while (i + 8 <= eend) {
            int s0 = csr[i], s1 = csr[i + 1], s2 = csr[i + 2], s3 = csr[i + 3];
            int s4 = csr[i + 4], s5 = csr[i + 5], s6 = csr[i + 6], s7 = csr[i + 7];
            unsigned g0 = H[(long long)s0 * 64 + lane];
            unsigned g1 = H[(long long)s1 * 64 + lane];
            unsigned g2 = H[(long long)s2 * 64 + lane];
            unsigned g3 = H[(long long)s3 * 64 + lane];
            unsigned g4 = H[(long long)s4 * 64 + lane];
            unsigned g5 = H[(long long)s5 * 64 + lane];
            unsigned g6 = H[(long long)s6 * 64 + lane];
            unsigned g7 = H[(long long)s7 * 64 + lane];
            while (i >= nend) A1_FLUSH_ADV();
            { float2 f = unpackbf2(g0); acc.x += f.x; acc.y += f.y; }
            while (i + 1 >= nend) A1_FLUSH_ADV();
            { float2 f = unpackbf2(g1); acc.x += f.x; acc.y += f.y; }
            while (i + 2 >= nend) A1_FLUSH_ADV();
            { float2 f = unpackbf2(g2); acc.x += f.x; acc.y += f.y; }
            while (i + 3 >= nend) A1_FLUSH_ADV();
            { float2 f = unpackbf2(g3); acc.x += f.x; acc.y += f.y; }
            while (i + 4 >= nend) A1_FLUSH_ADV();
            { float2 f = unpackbf2(g4); acc.x += f.x; acc.y += f.y; }
            while (i + 5 >= nend) A1_FLUSH_ADV();
            { float2 f = unpackbf2(g5); acc.x += f.x; acc.y += f.y; }
            while (i + 6 >= nend) A1_FLUSH_ADV();
            { float2 f = unpackbf2(g6); acc.x += f.x; acc.y += f.y; }
            while (i + 7 >= nend) A1_FLUSH_ADV();
            { float2 f = unpackbf2(g7); acc.x += f.x; acc.y += f.y; }
            i += 8;
        }
        while (i < eend) {
            int s0 = csr[i];
            unsigned g0 = H[(long long)s0 * 64 + lane];
            while (i >= nend) A1_FLUSH_ADV();
            { float2 f = unpackbf2(g0); acc.x += f.x; acc.y += f.y; }
            ++i;
        }
        for (;;) {  // trailing flushes
            float ox = dncur * acc.x, oy = dncur * acc.y;
            X1[(long long)n * 64 + lane] = packbf2(ox, oy);
            bs.x += ox; bs.y += oy;
            bq.x += ox * ox; bq.y += oy * oy;
            ++n;
            if (n >= n1) break;
            dncur = dinv[n];
            acc = unpackbf2(hnext);
            int np_ = (n + 1 < N) ? (n + 1) : (N - 1);
            hnext = H[(long long)np_ * 64 + lane];
        }
    }
    __shared__ float2 ls[256], lq[256];
    ls[threadIdx.x] = bs; lq[threadIdx.x] = bq;
    __syncthreads();
    if (threadIdx.x < 64) {
        float2 s = ls[threadIdx.x], q = lq[threadIdx.x];
#pragma unroll
        for (int j = 64; j < 256; j += 64) {
            float2 a = ls[threadIdx.x + j], b = lq[threadIdx.x + j];
            s.x += a.x; s.y += a.y; q.x += b.x; q.y += b.y;
        }
        atomicAdd(&bnsum[threadIdx.x * 2 + 0], s.x);
        atomicAdd(&bnsum[threadIdx.x * 2 + 1], s.y);
        atomicAdd(&bnsq[threadIdx.x * 2 + 0], q.x);
        atomicAdd(&bnsq[threadIdx.x * 2 + 1], q.y);
    }
}

__global__ __launch_bounds__(128) void bnfinal_k(const float* bnsum, const float* bnsq,
                                                 const float* __restrict__ gamma,
                                                 const float* __restrict__ beta,
                                                 float* scale, float* shift, int N) {
    int c = threadIdx.x;
    float mu = bnsum[c] / (float)N;
    float var = bnsq[c] / (float)N - mu * mu;
    var = var > 0.f ? var : 0.f;
    float sc = gamma[c] * rsqrtf(var + BN_EPS);
    scale[c] = sc;
    shift[c] = beta[c] - mu * sc;
}

// ---------------- GEMM2 (MFMA): H2' = dinv .* bf16(relu(BN(X1)) @ W2) ----------------
__global__ __launch_bounds__(256) void gemm2_k(const unsigned* __restrict__ X1,
                                               const unsigned short* __restrict__ W2t,
                                               const float* __restrict__ scale,
                                               const float* __restrict__ shift,
                                               const float* __restrict__ dinv,
                                               unsigned* __restrict__ H2, int N) {
    __shared__ char smem[64 * ROWB + 112 * ROWB];
    __shared__ float scs[128], shs[128];
    char* Xs = smem;
    char* Wt = smem + 64 * ROWB;
    int tid = threadIdx.x;
    int row0 = blockIdx.x * 64;
    if (tid < 128) { scs[tid] = scale[tid]; shs[tid] = shift[tid]; }
    {
        const uint4* Wg = (const uint4*)W2t;
#pragma unroll
        for (int i = 0; i < 7; ++i) {
            int idx = i * 256 + tid;
            uint4 u = Wg[idx];
            *(uint4*)(Wt + (idx >> 4) * ROWB + (idx & 15) * 16) = u;
        }
    }
    __syncthreads();
    {
        const uint4* Xg = (const uint4*)X1;
#pragma unroll
        for (int i = 0; i < 4; ++i) {
            int idx = i * 256 + tid;
            int r = idx >> 4, kc = idx & 15;
            int grow = row0 + r; if (grow >= N) grow = N - 1;
            uint4 u = Xg[(long long)grow * 16 + kc];
            uint4 o;
#pragma unroll
            for (int jj = 0; jj < 4; ++jj) {
                float2 f = unpackbf2((&u.x)[jj]);
                int k = kc * 8 + jj * 2;
                float v0 = f.x * scs[k] + shs[k];
                float v1 = f.y * scs[k + 1] + shs[k + 1];
                (&o.x)[jj] = packbf2(v0 > 0.f ? v0 : 0.f, v1 > 0.f ? v1 : 0.f);
            }
            *(uint4*)(Xs + r * ROWB + kc * 16) = o;
        }
    }
    __syncthreads();
    int w = tid >> 6, l = tid & 63;
    int arow = w * 16 + (l & 15);
    int koff = (l >> 4) * 16;
    f32x4 acc[7];
#pragma unroll
    for (int ct = 0; ct < 7; ++ct)
#pragma unroll
        for (int r = 0; r < 4; ++r) acc[ct][r] = 0.f;
#pragma unroll
    for (int ks = 0; ks < 4; ++ks) {
        int kb = ks * 64 + koff;
        bf16x8 a = *(const bf16x8*)(Xs + arow * ROWB + kb);
#pragma unroll
        for (int ct = 0; ct < 7; ++ct) {
            bf16x8 b = *(const bf16x8*)(Wt + (ct * 16 + (l & 15)) * ROWB + kb);
            acc[ct] = __builtin_amdgcn_mfma_f32_16x16x32_bf16(a, b, acc[ct], 0, 0, 0);
        }
    }
    __syncthreads();
    {
        int crow0 = w * 16 + (l >> 4) * 4;
        int ccol = l & 15;
#pragma unroll
        for (int ct = 0; ct < 7; ++ct)
#pragma unroll
            for (int r = 0; r < 4; ++r)
                *(unsigned short*)(Xs + (crow0 + r) * ROWB + (ct * 16 + ccol) * 2) = f2bf(acc[ct][r]);
    }
    __syncthreads();
#pragma unroll
    for (int i = 0; i < 13; ++i) {
        int idx = i * 256 + tid;
        if (idx < 3200) {
            int r = idx / 50, cu = idx - r * 50;
            int grow = row0 + r;
            if (grow < N) {
                float2 f = unpackbf2(*(unsigned*)(Xs + r * ROWB + cu * 4));
                float d = dinv[grow];
                H2[(long long)grow * 50 + cu] = packbf2(f.x * d, f.y * d);
            }
        }
    }
}

// ---------------- agg2 + bias + segment_max pool (batch sorted) ----------------
#define NINF (-__builtin_inff())
#define A2_FLUSH_ADV()                                                  \
    do {                                                                \
        float vx_ = dncur * acc.x + bf.x, vy_ = dncur * acc.y + bf.y;   \
        int gb_ = batch[n];                                             \
        if (gb_ != gcur) {                                              \
            long long pb_ = (long long)gcur * D_OUT + lane * 2;         \
            atomicMax(&pool[pb_], fmap(mx));                            \
            atomicMax(&pool[pb_ + 1], fmap(my));                        \
            gcur = gb_; mx = NINF; my = NINF;                           \
        }                                                               \
        mx = mx > vx_ ? mx : vx_; my = my > vy_ ? my : vy_;             \
        ++n;                                                            \
        nend = off[n + 1];                                              \
        dncur = dinv[n];                                                \
        acc = unpackbf2(hnext);                                         \
        int np_ = (n + 1 < N) ? (n + 1) : (N - 1);                      \
        hnext = H2[(long long)np_ * 50 + lane];                         \
    } while (0)

__global__ __launch_bounds__(256) void agg2pool_k(const unsigned* __restrict__ H2,
                                                  const int* __restrict__ off,
                                                  const int* __restrict__ csr,
                                                  const float* __restrict__ dinv,
                                                  const int* __restrict__ batch,
                                                  const float* __restrict__ b2,
                                                  unsigned* __restrict__ pool,
                                                  int N, int chunk) {
    int grp = blockIdx.x * 4 + (threadIdx.x >> 6);
    int lane = threadIdx.x & 63;
    if (lane >= 50) return;
    int n0 = grp * chunk;
    int n1 = n0 + chunk; if (n1 > N) n1 = N;
    if (n0 >= n1) return;
    float2 bf = ((const float2*)b2)[lane];
    float mx = NINF, my = NINF;
    int gcur = batch[n0];
    int n = n0;
    int i = off[n0];
    int eend = off[n1];
    int nend = off[n0 + 1];
    float dncur = dinv[n0];
    float2 acc = unpackbf2(H2[(long long)n0 * 50 + lane]);
    int np0 = (n0 + 1 < N) ? (n0 + 1) : (N - 1);
    unsigned hnext = H2[(long long)np0 * 50 + lane];
    while (i + 8 <= eend) {
        int s0 = csr[i], s1 = csr[i + 1], s2 = csr[i + 2], s3 = csr[i + 3];
        int s4 = csr[i + 4], s5 = csr[i + 5], s6 = csr[i + 6], s7 = csr[i + 7];
        unsigned g0 = H2[(long long)s0 * 50 + lane];
        unsigned g1 = H2[(long long)s1 * 50 + lane];
        unsigned g2 = H2[(long long)s2 * 50 + lane];
        unsigned g3 = H2[(long long)s3 * 50 + lane];
        unsigned g4 = H2[(long long)s4 * 50 + lane];
        unsigned g5 = H2[(long long)s5 * 50 + lane];
        unsigned g6 = H2[(long long)s6 * 50 + lane];
        unsigned g7 = H2[(long long)s7 * 50 + lane];
        while (i >= nend) A2_FLUSH_ADV();
        { float2 f = unpackbf2(g0); acc.x += f.x; acc.y += f.y; }
        while (i + 1 >= nend) A2_FLUSH_ADV();
        { float2 f = unpackbf2(g1); acc.x += f.x; acc.y += f.y; }
        while (i + 2 >= nend) A2_FLUSH_ADV();
        { float2 f = unpackbf2(g2); acc.x += f.x; acc.y += f.y; }
        while (i + 3 >= nend) A2_FLUSH_ADV();
        { float2 f = unpackbf2(g3); acc.x += f.x; acc.y += f.y; }
        while (i + 4 >= nend) A2_FLUSH_ADV();
        { float2 f = unpackbf2(g4); acc.x += f.x; acc.y += f.y; }
        while (i + 5 >= nend) A2_FLUSH_ADV();
        { float2 f = unpackbf2(g5); acc.x += f.x; acc.y += f.y; }
        while (i + 6 >= nend) A2_FLUSH_ADV();
        { float2 f = unpackbf2(g6); acc.x += f.x; acc.y += f.y; }
        while (i + 7 >= nend) A2_FLUSH_ADV();
        { float2 f = unpackbf2(g7); acc.x += f.x; acc.y += f.y; }
        i += 8;
    }
    while (i < eend) {
        int s0 = csr[i];
        unsigned g0 = H2[(long long)s0 * 50 + lane];
        while (i >= nend) A2_FLUSH_ADV();
        { float2 f = unpackbf2(g0); acc.x += f.x; acc.y += f.y; }
        ++i;
    }
    for (;;) {  // trailing flushes
        float vx_ = dncur * acc.x + bf.x, vy_ = dncur * acc.y + bf.y;
        int gb_ = batch[n];
        if (gb_ != gcur) {
            long long pb_ = (long long)gcur * D_OUT + lane * 2;
            atomicMax(&pool[pb_], fmap(mx));
            atomicMax(&pool[pb_ + 1], fmap(my));
            gcur = gb_; mx = NINF; my = NINF;
        }
        mx = mx > vx_ ? mx : vx_; my = my > vy_ ? my : vy_;
        ++n;
        if (n >= n1) break;
        dncur = dinv[n];
        acc = unpackbf2(hnext);
        int np_ = (n + 1 < N) ? (n + 1) : (N - 1);
        hnext = H2[(long long)np_ * 50 + lane];
    }
    long long pb = (long long)gcur * D_OUT + lane * 2;
    atomicMax(&pool[pb], fmap(mx));
    atomicMax(&pool[pb + 1], fmap(my));
}

__global__ __launch_bounds__(256) void pool_final_k(const unsigned* __restrict__ pool,
                                                    float* __restrict__ out, int P) {
    int i = blockIdx.x * 256 + threadIdx.x;
    if (i < P) out[i] = funmap(pool[i]);
}

// ---------------- launch ----------------
extern "C" void kernel_launch(void* const* d_in, const int* in_sizes, int n_in,
                              void* d_out, int out_size, void* d_ws, size_t ws_size,
                              hipStream_t stream) {
    const float* X     = (const float*)d_in[0];
    const int*   eidx  = (const int*)d_in[1];
    const int*   batch = (const int*)d_in[2];
    const float* W1    = (const float*)d_in[4];
    // d_in[5] = b1: cancels inside batch_norm
    const float* gamma = (const float*)d_in[6];
    const float* beta  = (const float*)d_in[7];
    const float* W2    = (const float*)d_in[8];
    const float* b2    = (const float*)d_in[9];

    const int N = in_sizes[0] / D_HID;     // 200000
    const int E = in_sizes[1] / 2;         // 600000
    const int P = out_size;                // num_graphs * 100
    const int* src = eidx;
    const int* dst = eidx + E;

    // workspace layout
    char* p = (char*)d_ws;
    auto alloc = [&](size_t bytes) { char* q = p; p += (bytes + 255) & ~(size_t)255; return q; };
    int*      deg    = (int*)alloc((size_t)N * 4);
    int*      cursor = (int*)alloc((size_t)N * 4);
    int*      off    = (int*)alloc((size_t)(N + 1) * 4);
    int*      btot   = (int*)alloc(256 * 4);
    int*      csr    = (int*)alloc((size_t)E * 4);
    float*    dinv   = (float*)alloc((size_t)N * 4);
    float*    bnsum  = (float*)alloc(128 * 4);
    float*    bnsq   = (float*)alloc(128 * 4);
    float*    scale  = (float*)alloc(128 * 4);
    float*    shift  = (float*)alloc(128 * 4);
    unsigned short* W1t = (unsigned short*)alloc(16384 * 2);
    unsigned short* W2t = (unsigned short*)alloc(14336 * 2);
    unsigned* pool   = (unsigned*)alloc((size_t)P * 4);
    unsigned* A      = (unsigned*)alloc((size_t)N * 128 * 2);  // H' bf16 (then H2', stride 100)
    unsigned* B      = (unsigned*)alloc((size_t)N * 128 * 2);  // X1 bf16

    const int nb1 = (N + SCAN_EPB - 1) / SCAN_EPB;
    const int initN = (N > P ? N : P);

    init_k<<<(initN + 255) / 256, 256, 0, stream>>>(deg, cursor, pool, bnsum, bnsq,
                                                    W1, W2, W1t, W2t, N, P);
    deg_k<<<(E + 255) / 256, 256, 0, stream>>>(dst, deg, E);
    scan1_k<<<nb1, 256, 0, stream>>>(deg, off, btot, N);
    scan2_k<<<1, 256, 0, stream>>>(btot, nb1, off, N, E);
    scan3_dinv_k<<<(N + 255) / 256, 256, 0, stream>>>(off, btot, deg, dinv, N);
    fill_k<<<(E + 255) / 256, 256, 0, stream>>>(src, dst, off, cursor, csr, E);

    const int nblk_g = (N + 63) / 64;
    gemm1_k<<<nblk_g, 256, 0, stream>>>(X, W1t, dinv, A, N);

    const int nblk_agg = 2048;
    const int ngrp = nblk_agg * 4;
    const int chunk = (N + ngrp - 1) / ngrp;   // 25
    agg1_k<<<nblk_agg, 256, 0, stream>>>(A, off, csr, dinv, B, bnsum, bnsq, N, chunk);
    bnfinal_k<<<1, 128, 0, stream>>>(bnsum, bnsq, gamma, beta, scale, shift, N);

    gemm2_k<<<nblk_g, 256, 0, stream>>>(B, W2t, scale, shift, dinv, A, N);

    agg2pool_k<<<nblk_agg, 256, 0, stream>>>(A, off, csr, dinv, batch, b2, pool, N, chunk);
    pool_final_k<<<(P + 255) / 256, 256, 0, stream>>>(pool, (float*)d_out, P);
}